// Round 1
// baseline (1134.127 us; speedup 1.0000x reference)
//
#include <hip/hip_runtime.h>

// HT model: MLP (64->128->64->32->32) -> leaf contraction -> 5 tree levels -> top.
// All fp32 (tree squares relative errors ~2^6; bf16 would blow the 2% absmax budget).
// One generic tiled SGEMM kernel used for every stage.
//
// Requires ws_size >= 192 MB (3 x 64MB ping-pong regions).

#define TILE 128
#define KC 16

__global__ __launch_bounds__(256) void ht_gemm(
    const float* __restrict__ A,
    const float* __restrict__ Bw,
    const float* __restrict__ bias,
    float* __restrict__ C,
    int K, int Gtot,
    long long a_bstride, long long a_nstride, int prod_mode,
    long long w_nstride, int w_trans,
    long long c_bstride, long long c_nstride,
    int do_relu)
{
    __shared__ float As[KC][TILE];
    __shared__ float Bs[KC][TILE];

    const int tid = threadIdx.x;
    const int b0 = blockIdx.x * TILE;
    const int g0 = blockIdx.y * TILE;
    const int n  = blockIdx.z;

    const int bpos = (tid >> 4) << 3;   // 0..120 step 8
    const int gpos = (tid & 15) << 3;   // 0..120 step 8

    const int sb  = tid & 127;          // staging row
    const int sa4 = tid >> 7;           // 0/1

    const float* arow0 = A + (size_t)(b0 + sb) * a_bstride
                           + (size_t)(prod_mode ? 2 * n : n) * a_nstride;
    const float* arow1 = arow0 + a_nstride;   // second row for product mode
    const float* wbase = Bw + (size_t)n * w_nstride;

    float acc[8][8];
#pragma unroll
    for (int i = 0; i < 8; ++i)
#pragma unroll
        for (int j = 0; j < 8; ++j) acc[i][j] = 0.f;

    for (int k0 = 0; k0 < K; k0 += KC) {
        // ---- stage A tile (transposed): As[a][bb] = A(b0+bb, k0+a), optionally
        //      the elementwise product of the two child rows (tree levels).
#pragma unroll
        for (int r = 0; r < 2; ++r) {
            const int a4 = r * 2 + sa4;      // 0..3
            const int a  = k0 + a4 * 4;
            float4 v = *(const float4*)(arow0 + a);
            if (prod_mode) {
                float4 w = *(const float4*)(arow1 + a);
                v.x *= w.x; v.y *= w.y; v.z *= w.z; v.w *= w.w;
            }
            As[a4 * 4 + 0][sb] = v.x;
            As[a4 * 4 + 1][sb] = v.y;
            As[a4 * 4 + 2][sb] = v.z;
            As[a4 * 4 + 3][sb] = v.w;
        }
        // ---- stage B tile: Bs[a][gg] = W(g0+gg, k0+a)
        if (!w_trans) {
            // weights stored [g][K] (P matrices): contiguous in K
#pragma unroll
            for (int r = 0; r < 2; ++r) {
                const int a4 = r * 2 + sa4;
                const int a  = k0 + a4 * 4;
                const int g  = g0 + sb;
                float4 v;
                if (g < Gtot) v = *(const float4*)(wbase + (size_t)g * K + a);
                else          v = make_float4(0.f, 0.f, 0.f, 0.f);
                Bs[a4 * 4 + 0][sb] = v.x;
                Bs[a4 * 4 + 1][sb] = v.y;
                Bs[a4 * 4 + 2][sb] = v.z;
                Bs[a4 * 4 + 3][sb] = v.w;
            }
        } else {
            // weights stored [K][Gtot] (torch Linear (in,out)): contiguous in g
#pragma unroll
            for (int r = 0; r < 2; ++r) {
                const int slot = r * 256 + tid;    // 0..511
                const int ar   = slot >> 5;        // 0..15
                const int gg4  = (slot & 31) * 4;  // 0..124
                const int g    = g0 + gg4;
                float4 v;
                if (g < Gtot) v = *(const float4*)(wbase + (size_t)(k0 + ar) * Gtot + g);
                else          v = make_float4(0.f, 0.f, 0.f, 0.f);
                *(float4*)&Bs[ar][gg4] = v;
            }
        }
        __syncthreads();
#pragma unroll
        for (int a = 0; a < KC; ++a) {
            float4 a0 = *(const float4*)&As[a][bpos];
            float4 a1 = *(const float4*)&As[a][bpos + 4];
            float4 q0 = *(const float4*)&Bs[a][gpos];
            float4 q1 = *(const float4*)&Bs[a][gpos + 4];
            float av[8] = {a0.x, a0.y, a0.z, a0.w, a1.x, a1.y, a1.z, a1.w};
            float bv[8] = {q0.x, q0.y, q0.z, q0.w, q1.x, q1.y, q1.z, q1.w};
#pragma unroll
            for (int i = 0; i < 8; ++i)
#pragma unroll
                for (int j = 0; j < 8; ++j)
                    acc[i][j] = fmaf(av[i], bv[j], acc[i][j]);
        }
        __syncthreads();
    }

    // ---- epilogue: bias + relu + store (g bounds-checked on partial tiles)
    float bvals[8];
#pragma unroll
    for (int j = 0; j < 8; ++j) {
        const int g = g0 + gpos + j;
        bvals[j] = (bias != nullptr && g < Gtot) ? bias[g] : 0.f;
    }
    const bool full = (g0 + TILE <= Gtot);
#pragma unroll
    for (int i = 0; i < 8; ++i) {
        const int b = b0 + bpos + i;
        float* crow = C + (size_t)b * c_bstride + (size_t)n * c_nstride;
        float o[8];
#pragma unroll
        for (int j = 0; j < 8; ++j) {
            float v = acc[i][j] + bvals[j];
            if (do_relu) v = fmaxf(v, 0.f);
            o[j] = v;
        }
        if (full) {
            *(float4*)(crow + g0 + gpos)     = make_float4(o[0], o[1], o[2], o[3]);
            *(float4*)(crow + g0 + gpos + 4) = make_float4(o[4], o[5], o[6], o[7]);
        } else {
#pragma unroll
            for (int j = 0; j < 8; ++j) {
                const int g = g0 + gpos + j;
                if (g < Gtot) crow[g] = o[j];
            }
        }
    }
}

extern "C" void kernel_launch(void* const* d_in, const int* in_sizes, int n_in,
                              void* d_out, int out_size, void* d_ws, size_t ws_size,
                              hipStream_t stream)
{
    const float* X    = (const float*)d_in[0];
    const float* W1   = (const float*)d_in[1];
    const float* b1   = (const float*)d_in[2];
    const float* W2   = (const float*)d_in[3];
    const float* b2   = (const float*)d_in[4];
    const float* W3   = (const float*)d_in[5];
    const float* b3   = (const float*)d_in[6];
    const float* W4   = (const float*)d_in[7];
    const float* b4   = (const float*)d_in[8];
    const float* P0   = (const float*)d_in[9];
    const float* P1   = (const float*)d_in[10];
    const float* P2   = (const float*)d_in[11];
    const float* P3   = (const float*)d_in[12];
    const float* P4   = (const float*)d_in[13];
    const float* P5   = (const float*)d_in[14];
    const float* Ptop = (const float*)d_in[15];
    float* out = (float*)d_out;

    // 3 x 64MB regions (16M floats each): needs ws_size >= 192MB
    float* R0 = (float*)d_ws;
    float* R1 = R0 + (size_t)16 * 1024 * 1024;
    float* R2 = R1 + (size_t)16 * 1024 * 1024;

    // MLP scratch inside R0 (per 65536-token chunk): 32+16+8+8 = 64MB
    float* h1 = R0;                          // 65536*128
    float* h2 = h1 + (size_t)65536 * 128;    // 65536*64
    float* h3 = h2 + (size_t)65536 * 64;     // 65536*32
    float* F  = h3 + (size_t)65536 * 32;     // 65536*32

    float* t0 = R1;   // [4096][64][64]
    float* t1 = R2;   // [4096][32][128]
    float* t2 = R0;   // [4096][16][256]   (MLP scratch dead by now)
    float* t3 = R1;   // [4096][8][512]    (t0 dead)
    float* t4 = R2;   // [4096][4][512]    (t1 dead)
    float* t5 = R0;   // [4096][2][512]    (t2 dead)

    dim3 blk(256, 1, 1);

    // ---- MLP + leaf, chunked over 4 batch-chunks of 1024 (65536 tokens)
    for (int c = 0; c < 4; ++c) {
        const float* Xc = X + (size_t)c * 65536 * 64;
        // mlp1: 64 -> 128, relu
        ht_gemm<<<dim3(512, 1, 1), blk, 0, stream>>>(
            Xc, W1, b1, h1, 64, 128, 64, 0, 0, 0, 1, 128, 0, 1);
        // mlp2: 128 -> 64, relu
        ht_gemm<<<dim3(512, 1, 1), blk, 0, stream>>>(
            h1, W2, b2, h2, 128, 64, 128, 0, 0, 0, 1, 64, 0, 1);
        // mlp3: 64 -> 32, relu
        ht_gemm<<<dim3(512, 1, 1), blk, 0, stream>>>(
            h2, W3, b3, h3, 64, 32, 64, 0, 0, 0, 1, 32, 0, 1);
        // mlp4: 32 -> 32 (no relu)
        ht_gemm<<<dim3(512, 1, 1), blk, 0, stream>>>(
            h3, W4, b4, F, 32, 32, 32, 0, 0, 0, 1, 32, 0, 0);
        // leaf: t0[b,j,a] = sum_m P0[j,a,m] * F[b,j,m]
        ht_gemm<<<dim3(8, 1, 64), blk, 0, stream>>>(
            F, P0, nullptr, t0 + (size_t)c * 1024 * 4096,
            32, 64, 2048, 32, 0, 2048, 0, 4096, 64, 0);
    }

    // ---- tree levels: t_l[b,j,g] = sum_a P_l[j,g,a] * t[b,2j,a]*t[b,2j+1,a]
    // L1: 32 nodes, K=64, G=128
    ht_gemm<<<dim3(32, 1, 32), blk, 0, stream>>>(
        t0, P1, nullptr, t1, 64, 128, 4096, 64, 1, 8192, 0, 4096, 128, 0);
    // L2: 16 nodes, K=128, G=256
    ht_gemm<<<dim3(32, 2, 16), blk, 0, stream>>>(
        t1, P2, nullptr, t2, 128, 256, 4096, 128, 1, 32768, 0, 4096, 256, 0);
    // L3: 8 nodes, K=256, G=512
    ht_gemm<<<dim3(32, 4, 8), blk, 0, stream>>>(
        t2, P3, nullptr, t3, 256, 512, 4096, 256, 1, 131072, 0, 4096, 512, 0);
    // L4: 4 nodes, K=512, G=512
    ht_gemm<<<dim3(32, 4, 4), blk, 0, stream>>>(
        t3, P4, nullptr, t4, 512, 512, 4096, 512, 1, 262144, 0, 2048, 512, 0);
    // L5: 2 nodes, K=512, G=512
    ht_gemm<<<dim3(32, 4, 2), blk, 0, stream>>>(
        t4, P5, nullptr, t5, 512, 512, 2048, 512, 1, 262144, 0, 1024, 512, 0);
    // top: out[b,y] = sum_a Ptop[y,a] * t5[b,0,a]*t5[b,1,a]
    ht_gemm<<<dim3(32, 8, 1), blk, 0, stream>>>(
        t5, Ptop, nullptr, out, 512, 1000, 1024, 512, 1, 0, 0, 1000, 0, 0);
}

// Round 2
// 930.649 us; speedup vs baseline: 1.2186x; 1.2186x over previous
//
#include <hip/hip_runtime.h>

// HT model, fp32 throughout (tree squares relative error ~2^6; bf16 blows the
// 2% absmax budget — measured fp32 absmax is already at 55% of threshold).
//
// Layout strategy: ALL intermediates are feature-major, batch-contiguous:
//   t[node][feature][4096], h[node][feature][4096].
// GEMM computes C[n][g][b] = sum_k W[n][g][k] * A[n][k][b] with b contiguous,
// so A-staging and C-stores are perfectly coalesced. W/P matrices are small
// and L2-hot (strided reads are fine). X (fixed input layout) is transposed
// during mlp1's staging only.
//
// Requires ws_size >= 192 MB.

#define KC 16

template<int TB, int TG>
__global__ __launch_bounds__(256) void ht_gemm(
    const float* __restrict__ A, const float* __restrict__ W,
    const float* __restrict__ bias, float* __restrict__ C,
    int K, int Gtot,
    int a_n, int a_k, int a_rstride,  // a_rstride>0: rowmajor A (addr = n*a_n + b*a_rstride + k)
                                      // else colmajor (addr = n*a_n + k*a_k + b)
    int a_pair,                       // >0: elementwise-multiply with A at +a_pair (colmajor only)
    int w_n, int w_g, int w_kcontig,  // kcontig: addr = n*w_n + g*w_g + k ; else: addr = k*w_g + g
    int c_n, int c_g, int c_rowmajor, // colmajor: n*c_n + g*c_g + b ; rowmajor: b*c_g + g
    int relu)
{
    static_assert(TB * TG == 16384, "256 threads x 8x8 microtile");
    __shared__ float As[KC][TB + 4];
    __shared__ float Bs[KC][TG + 4];

    const int tid  = threadIdx.x;
    const int lane = tid & 63;
    const int wv   = tid >> 6;

    // wave-aware 8x8 lane tiling: per wave, WBG b-groups x WGG g-groups.
    constexpr int WBG = (TB >= 512) ? 16 : 8;
    constexpr int WGG = 64 / WBG;
    constexpr int BW  = (TB / 8) / WBG;   // waves tiled along b
    const int bpos = ((lane % WBG) + (wv % BW) * WBG) * 8;
    const int gpos = ((lane / WBG) + (wv / BW) * WGG) * 8;

    const int b0 = blockIdx.x * TB;
    const int g0 = blockIdx.y * TG;
    const int n  = blockIdx.z;

    const float* Abase = A + (size_t)n * a_n;
    const float* Wbase = W + (size_t)n * w_n;

    float acc[8][8];
#pragma unroll
    for (int i = 0; i < 8; ++i)
#pragma unroll
        for (int j = 0; j < 8; ++j) acc[i][j] = 0.f;

    for (int k0 = 0; k0 < K; k0 += KC) {
        // ---- stage A tile: As[k][b]
        if (a_rstride > 0) {
            // row-major A (X input): transpose on stage; 4 lanes share a 64B row chunk
            constexpr int NR = TB / 64;
#pragma unroll
            for (int r = 0; r < NR; ++r) {
                const int s   = r * 256 + tid;
                const int row = s >> 2;
                const int kk  = (s & 3) * 4;
                float4 v = *(const float4*)(Abase + (size_t)(b0 + row) * a_rstride + k0 + kk);
                As[kk + 0][row] = v.x;
                As[kk + 1][row] = v.y;
                As[kk + 2][row] = v.z;
                As[kk + 3][row] = v.w;
            }
        } else {
            // col-major A: fully coalesced float4 stream
            constexpr int NC = TB / 64;    // (KC*TB/4)/256
#pragma unroll
            for (int r = 0; r < NC; ++r) {
                const int s  = r * 256 + tid;
                const int kk = s / (TB / 4);
                const int bb = (s % (TB / 4)) * 4;
                const float* p = Abase + (size_t)(k0 + kk) * a_k + b0 + bb;
                float4 v = *(const float4*)p;
                if (a_pair > 0) {
                    float4 u = *(const float4*)(p + a_pair);
                    v.x *= u.x; v.y *= u.y; v.z *= u.z; v.w *= u.w;
                }
                *(float4*)&As[kk][bb] = v;
            }
        }
        // ---- stage W tile: Bs[k][g]
        if (w_kcontig) {
#pragma unroll 2
            for (int s = tid; s < 4 * TG; s += 256) {
                const int g  = s >> 2;
                const int kk = (s & 3) * 4;
                float4 v;
                if (g0 + g < Gtot) v = *(const float4*)(Wbase + (size_t)(g0 + g) * w_g + k0 + kk);
                else               v = make_float4(0.f, 0.f, 0.f, 0.f);
                Bs[kk + 0][g] = v.x;
                Bs[kk + 1][g] = v.y;
                Bs[kk + 2][g] = v.z;
                Bs[kk + 3][g] = v.w;
            }
        } else {
#pragma unroll 2
            for (int s = tid; s < 4 * TG; s += 256) {
                const int kk = s / (TG / 4);
                const int gg = (s % (TG / 4)) * 4;
                float4 v = *(const float4*)(Wbase + (size_t)(k0 + kk) * w_g + g0 + gg);
                *(float4*)&Bs[kk][gg] = v;
            }
        }
        __syncthreads();
#pragma unroll
        for (int a = 0; a < KC; ++a) {
            float av[8], bv[8];
            *(float4*)&av[0] = *(const float4*)&As[a][bpos];
            *(float4*)&av[4] = *(const float4*)&As[a][bpos + 4];
            *(float4*)&bv[0] = *(const float4*)&Bs[a][gpos];
            *(float4*)&bv[4] = *(const float4*)&Bs[a][gpos + 4];
#pragma unroll
            for (int i = 0; i < 8; ++i)
#pragma unroll
                for (int j = 0; j < 8; ++j)
                    acc[i][j] = fmaf(av[i], bv[j], acc[i][j]);
        }
        __syncthreads();
    }

    // ---- epilogue
    if (!c_rowmajor) {
        float bvals[8];
#pragma unroll
        for (int j = 0; j < 8; ++j) {
            const int g = g0 + gpos + j;
            bvals[j] = (bias != nullptr && g < Gtot) ? bias[g] : 0.f;
        }
#pragma unroll
        for (int j = 0; j < 8; ++j) {
            const int g = g0 + gpos + j;
            if (g < Gtot) {
                float* p = C + (size_t)n * c_n + (size_t)g * c_g + b0 + bpos;
                float o[8];
#pragma unroll
                for (int i = 0; i < 8; ++i) {
                    float v = acc[i][j] + bvals[j];
                    if (relu) v = fmaxf(v, 0.f);
                    o[i] = v;
                }
                *(float4*)(p)     = make_float4(o[0], o[1], o[2], o[3]);
                *(float4*)(p + 4) = make_float4(o[4], o[5], o[6], o[7]);
            }
        }
    } else {
        // final output: out[b][y] row-major
#pragma unroll
        for (int i = 0; i < 8; ++i) {
            float* p = C + (size_t)(b0 + bpos + i) * c_g;
#pragma unroll
            for (int j = 0; j < 8; ++j) {
                const int g = g0 + gpos + j;
                if (g < Gtot) p[g] = acc[i][j];
            }
        }
    }
}

extern "C" void kernel_launch(void* const* d_in, const int* in_sizes, int n_in,
                              void* d_out, int out_size, void* d_ws, size_t ws_size,
                              hipStream_t stream)
{
    const float* X    = (const float*)d_in[0];
    const float* W1   = (const float*)d_in[1];
    const float* b1   = (const float*)d_in[2];
    const float* W2   = (const float*)d_in[3];
    const float* b2   = (const float*)d_in[4];
    const float* W3   = (const float*)d_in[5];
    const float* b3   = (const float*)d_in[6];
    const float* W4   = (const float*)d_in[7];
    const float* b4   = (const float*)d_in[8];
    const float* P0   = (const float*)d_in[9];
    const float* P1   = (const float*)d_in[10];
    const float* P2   = (const float*)d_in[11];
    const float* P3   = (const float*)d_in[12];
    const float* P4   = (const float*)d_in[13];
    const float* P5   = (const float*)d_in[14];
    const float* Ptop = (const float*)d_in[15];
    float* out = (float*)d_out;

    float* base = (float*)d_ws;
    const size_t M16 = (size_t)16 * 1024 * 1024;
    // region plan (floats):
    //   [0,16M)    : t0 [64][64][4096]      -> later t2 [16][256][4096], then t5 [2][512][4096]
    //   [16M,32M)  : h2|h3|F chunk scratch  -> later t4 [4][512][4096]
    //   [32M,48M)  : h1 chunk [32][128][4096] -> later t1 [32][128][4096], then t3 [8][512][4096]
    float* t0 = base;
    float* h2 = base + M16;
    float* h3 = h2 + (size_t)8 * 1024 * 1024;
    float* F  = h3 + (size_t)4 * 1024 * 1024;
    float* h1 = base + 2 * M16;
    float* t1 = base + 2 * M16;
    float* t2 = base;
    float* t3 = base + 2 * M16;
    float* t4 = base + M16;
    float* t5 = base;

    dim3 blk(256, 1, 1);

    // ---- MLP + leaf, 2 chunks of 32 nodes
    for (int c = 0; c < 2; ++c) {
        const float* Xc = X + (size_t)c * 32 * 64;
        // mlp1: 64 -> 128, relu.  A = X row-major (transpose-stage)
        ht_gemm<128, 128><<<dim3(32, 1, 32), blk, 0, stream>>>(
            Xc, W1, b1, h1, 64, 128,
            64, 0, 4096, 0,
            0, 128, 0,
            524288, 4096, 0, 1);
        // mlp2: 128 -> 64, relu
        ht_gemm<256, 64><<<dim3(16, 1, 32), blk, 0, stream>>>(
            h1, W2, b2, h2, 128, 64,
            524288, 4096, 0, 0,
            0, 64, 0,
            262144, 4096, 0, 1);
        // mlp3: 64 -> 32, relu
        ht_gemm<512, 32><<<dim3(8, 1, 32), blk, 0, stream>>>(
            h2, W3, b3, h3, 64, 32,
            262144, 4096, 0, 0,
            0, 32, 0,
            131072, 4096, 0, 1);
        // mlp4: 32 -> 32
        ht_gemm<512, 32><<<dim3(8, 1, 32), blk, 0, stream>>>(
            h3, W4, b4, F, 32, 32,
            131072, 4096, 0, 0,
            0, 32, 0,
            131072, 4096, 0, 0);
        // leaf: t0[j][a][b] = sum_m P0[j][a][m] * F[j][m][b]
        ht_gemm<256, 64><<<dim3(16, 1, 32), blk, 0, stream>>>(
            F, P0 + (size_t)c * 65536, nullptr, t0 + (size_t)c * 8388608, 32, 64,
            131072, 4096, 0, 0,
            2048, 32, 1,
            262144, 4096, 0, 0);
    }

    // ---- tree levels: t_l[n][g][b] = sum_a P_l[n][g][a] * t[2n][a][b]*t[2n+1][a][b]
    // L1: 32 nodes, K=64, G=128
    ht_gemm<128, 128><<<dim3(32, 1, 32), blk, 0, stream>>>(
        t0, P1, nullptr, t1, 64, 128,
        524288, 4096, 0, 262144,
        8192, 64, 1,
        524288, 4096, 0, 0);
    // L2: 16 nodes, K=128, G=256
    ht_gemm<128, 128><<<dim3(32, 2, 16), blk, 0, stream>>>(
        t1, P2, nullptr, t2, 128, 256,
        1048576, 4096, 0, 524288,
        32768, 128, 1,
        1048576, 4096, 0, 0);
    // L3: 8 nodes, K=256, G=512
    ht_gemm<128, 128><<<dim3(32, 4, 8), blk, 0, stream>>>(
        t2, P3, nullptr, t3, 256, 512,
        2097152, 4096, 0, 1048576,
        131072, 256, 1,
        2097152, 4096, 0, 0);
    // L4: 4 nodes, K=512, G=512
    ht_gemm<128, 128><<<dim3(32, 4, 4), blk, 0, stream>>>(
        t3, P4, nullptr, t4, 512, 512,
        4194304, 4096, 0, 2097152,
        262144, 512, 1,
        2097152, 4096, 0, 0);
    // L5: 2 nodes, K=512, G=512
    ht_gemm<128, 128><<<dim3(32, 4, 2), blk, 0, stream>>>(
        t4, P5, nullptr, t5, 512, 512,
        4194304, 4096, 0, 2097152,
        262144, 512, 1,
        2097152, 4096, 0, 0);
    // top: out[b][y] = sum_a Ptop[y][a] * t5[0][a][b]*t5[1][a][b]
    ht_gemm<128, 128><<<dim3(32, 8, 1), blk, 0, stream>>>(
        t5, Ptop, nullptr, out, 512, 1000,
        0, 4096, 0, 2097152,
        0, 512, 1,
        0, 1000, 1, 0);
}

// Round 3
// 700.561 us; speedup vs baseline: 1.6189x; 1.3284x over previous
//
#include <hip/hip_runtime.h>

// HT model via exact 3-way bf16 split + MFMA (gfx950).
// fp32 x = h + m + l (each bf16, split is EXACT: 3x8 = 24 mantissa bits).
// Product x*y: keep 8 of 9 cross terms (drop l*l <= 2^-32) on
// v_mfma_f32_16x16x32_bf16. h*h accumulates in acc_hi, the 7 small terms in
// acc_lo (their roundings are relative to a 2^-8-scale sum) -> fp32-quality.
//
// Layouts: all intermediates fp32, b-major [node][b][feat] (k contiguous).
// Weights pre-split per call into bf16 planes [3][rows][K] in d_ws.
// Needs ws_size >= 185 MB.

typedef short short8 __attribute__((ext_vector_type(8)));
typedef float f4 __attribute__((ext_vector_type(4)));

__device__ __forceinline__ unsigned bf16_rne(float x) {
    unsigned u = __float_as_uint(x);
    return (u + 0x7FFFu + ((u >> 16) & 1u)) >> 16;
}
__device__ __forceinline__ float bf16_f(unsigned h) {
    return __uint_as_float(h << 16);
}
__device__ __forceinline__ void split3(float x, unsigned& h, unsigned& m, unsigned& l) {
    h = bf16_rne(x);
    float r1 = x - bf16_f(h);      // exact (Sterbenz)
    m = bf16_rne(r1);
    float r2 = r1 - bf16_f(m);     // exact; r2 has <= 8 significant bits
    l = bf16_rne(r2);              // exact
}

// ---------------- weight pre-split ----------------
struct Seg { const float* src; long dst; int rows; int K; int trans; int blk0; };
struct SegTable { Seg s[11]; };

__global__ __launch_bounds__(256) void presplit(SegTable T, unsigned short* P) {
    int blk = blockIdx.x;
    int si = 0;
#pragma unroll
    for (int i = 1; i < 11; ++i) if (blk >= T.s[i].blk0) si = i;
    Seg d = T.s[si];
    long NE = (long)d.rows * d.K;
    long e0 = (long)(blk - d.blk0) * 1024 + threadIdx.x * 4;
    if (e0 >= NE) return;
    int g = (int)(e0 / d.K);
    int k = (int)(e0 - (long)g * d.K);
    float v[4];
    if (!d.trans) {
        float4 t = *(const float4*)(d.src + e0);
        v[0] = t.x; v[1] = t.y; v[2] = t.z; v[3] = t.w;
    } else {
#pragma unroll
        for (int i = 0; i < 4; ++i) v[i] = d.src[(long)(k + i) * d.rows + g];
    }
    unsigned h[4], m[4], l[4];
#pragma unroll
    for (int i = 0; i < 4; ++i) split3(v[i], h[i], m[i], l[i]);
    unsigned short* b0 = P + d.dst + e0;
    uint2 ph = { h[0] | (h[1] << 16), h[2] | (h[3] << 16) };
    uint2 pm = { m[0] | (m[1] << 16), m[2] | (m[3] << 16) };
    uint2 pl = { l[0] | (l[1] << 16), l[2] | (l[3] << 16) };
    *(uint2*)(b0)          = ph;
    *(uint2*)(b0 + NE)     = pm;
    *(uint2*)(b0 + 2 * NE) = pl;
}

// ---------------- main GEMM: C[z][b][g] = sum_k W[z][g][k] * Act[z][b][k] ----------------
// BG = 128 or 64. Block 128(b) x BG(g), 4 waves in 2x2, K-chunk 32.
template<int BG>
__global__ __launch_bounds__(256, 2) void ht_mm(
    const float* __restrict__ Act, const unsigned short* __restrict__ Wp,
    const float* __restrict__ bias, float* __restrict__ C,
    int K, int G,
    long act_z, long act_pair, int act_rb,
    long w_plane,
    long c_z, int c_rb, int relu)
{
    constexpr int MT = (BG == 128) ? 4 : 2;
    __shared__ unsigned short Ap[3][128][40];
    __shared__ unsigned short Wq[3][BG][40];

    const int tid = threadIdx.x, lane = tid & 63, w = tid >> 6;
    const int quad = lane >> 4, l15 = lane & 15;
    const int wg = (w & 1) * (BG / 2);
    const int wb = (w >> 1) * 64;
    const int b0 = blockIdx.x * 128, g0 = blockIdx.y * BG, z = blockIdx.z;

    const float* act0 = Act + (long)z * act_z + (long)b0 * act_rb;
    const unsigned short* wbase = Wp + (long)z * ((long)G * K) + (long)g0 * K;

    f4 acch[MT][4], accl[MT][4];
#pragma unroll
    for (int m = 0; m < MT; ++m)
#pragma unroll
        for (int n = 0; n < 4; ++n) { acch[m][n] = (f4)0.f; accl[m][n] = (f4)0.f; }

    for (int k0 = 0; k0 < K; k0 += 32) {
        // ---- stage Act (fp32 -> split -> 3 bf16 planes), coalesced 128B rows
#pragma unroll
        for (int r = 0; r < 4; ++r) {
            int s = r * 256 + tid;
            int b = s >> 3, k4 = s & 7;
            const float* p = act0 + (long)b * act_rb + k0 + k4 * 4;
            float4 v = *(const float4*)p;
            if (act_pair) {
                float4 u = *(const float4*)(p + act_pair);
                v.x *= u.x; v.y *= u.y; v.z *= u.z; v.w *= u.w;
            }
            float e[4] = { v.x, v.y, v.z, v.w };
            unsigned h[4], m[4], l[4];
#pragma unroll
            for (int i = 0; i < 4; ++i) split3(e[i], h[i], m[i], l[i]);
            uint2 ph = { h[0] | (h[1] << 16), h[2] | (h[3] << 16) };
            uint2 pm = { m[0] | (m[1] << 16), m[2] | (m[3] << 16) };
            uint2 pl = { l[0] | (l[1] << 16), l[2] | (l[3] << 16) };
            *(uint2*)&Ap[0][b][k4 * 4] = ph;
            *(uint2*)&Ap[1][b][k4 * 4] = pm;
            *(uint2*)&Ap[2][b][k4 * 4] = pl;
        }
        // ---- stage W planes (already bf16), 16B chunks
#pragma unroll
        for (int c = tid; c < 3 * BG * 4; c += 256) {
            int sp = c / (BG * 4);
            int g  = (c >> 2) % BG;
            int q  = c & 3;
            const unsigned short* src = wbase + sp * w_plane + (long)g * K + k0 + q * 8;
            *(uint4*)&Wq[sp][g][q * 8] = *(const uint4*)src;
        }
        __syncthreads();
        // ---- fragments + 8 split-product MFMAs per tile pair
        short8 af[3][4];
#pragma unroll
        for (int sb = 0; sb < 3; ++sb)
#pragma unroll
            for (int n = 0; n < 4; ++n)
                af[sb][n] = *(const short8*)&Ap[sb][wb + n * 16 + l15][quad * 8];
#pragma unroll
        for (int sa = 0; sa < 3; ++sa) {
#pragma unroll
            for (int m = 0; m < MT; ++m) {
                short8 wf = *(const short8*)&Wq[sa][wg + m * 16 + l15][quad * 8];
                const int nsb = (sa == 2) ? 2 : 3;
#pragma unroll
                for (int sb = 0; sb < 3; ++sb) {
                    if (sb >= nsb) continue;
#pragma unroll
                    for (int n = 0; n < 4; ++n) {
                        if (sa == 0 && sb == 0)
                            acch[m][n] = __builtin_amdgcn_mfma_f32_16x16x32_bf16(
                                wf, af[sb][n], acch[m][n], 0, 0, 0);
                        else
                            accl[m][n] = __builtin_amdgcn_mfma_f32_16x16x32_bf16(
                                wf, af[sb][n], accl[m][n], 0, 0, 0);
                    }
                }
            }
        }
        __syncthreads();
    }
    // ---- epilogue: D[row=g=quad*4+reg][col=b=lane&15]
#pragma unroll
    for (int m = 0; m < MT; ++m) {
        int gb = g0 + wg + m * 16 + quad * 4;
        if (gb >= G) continue;
        float bv[4] = { 0.f, 0.f, 0.f, 0.f };
        if (bias) { float4 t = *(const float4*)(bias + gb); bv[0]=t.x; bv[1]=t.y; bv[2]=t.z; bv[3]=t.w; }
#pragma unroll
        for (int n = 0; n < 4; ++n) {
            int bb = b0 + wb + n * 16 + l15;
            float o[4];
#pragma unroll
            for (int r = 0; r < 4; ++r) {
                float v = acch[m][n][r] + accl[m][n][r] + bv[r];
                o[r] = relu ? fmaxf(v, 0.f) : v;
            }
            float* p = C + (long)z * c_z + (long)bb * c_rb + gb;
            *(float4*)p = make_float4(o[0], o[1], o[2], o[3]);
        }
    }
}

extern "C" void kernel_launch(void* const* d_in, const int* in_sizes, int n_in,
                              void* d_out, int out_size, void* d_ws, size_t ws_size,
                              hipStream_t stream)
{
    const float* X    = (const float*)d_in[0];
    const float* W1   = (const float*)d_in[1];
    const float* b1   = (const float*)d_in[2];
    const float* W2   = (const float*)d_in[3];
    const float* b2   = (const float*)d_in[4];
    const float* W3   = (const float*)d_in[5];
    const float* b3   = (const float*)d_in[6];
    const float* W4   = (const float*)d_in[7];
    const float* b4   = (const float*)d_in[8];
    const float* P0   = (const float*)d_in[9];
    const float* P1   = (const float*)d_in[10];
    const float* P2   = (const float*)d_in[11];
    const float* P3   = (const float*)d_in[12];
    const float* P4   = (const float*)d_in[13];
    const float* P5   = (const float*)d_in[14];
    const float* Ptop = (const float*)d_in[15];
    float* out = (float*)d_out;

    unsigned short* planes = (unsigned short*)d_ws;
    float* base = (float*)d_ws;
    // float offsets (planes occupy [0, 6291456) floats = 24 MB, used 24.42MB->pad ok)
    float* h1c = base + 6291456L;          // 64 MB chunk [131072][128]
    float* h2c = base + 23068672L;         // 32 MB [131072][64]
    float* h3c = base + 6291456L;          // 16 MB [131072][32] (h1c dead)
    float* Fc  = base + 10485760L;         // 16 MB [131072][32]
    float* t0  = base + 31457280L;         // 64 MB [64][4096][64]
    float* t1  = base + 6291456L;          // 64 MB [32][4096][128]
    float* t2  = base + 23068672L;         // 64 MB [16][4096][256]
    float* t3  = base + 6291456L;          // 64 MB [8][4096][512]
    float* t4  = base + 39845888L;         // 32 MB [4][4096][512]
    float* t5  = base + 23068672L;         // 16 MB [2][4096][512]

    // ---- pre-split all weights into bf16 planes (one launch)
    SegTable T;
    auto seg = [](const float* s, long dst, int rows, int K, int tr, int b0) {
        Seg d; d.src = s; d.dst = dst; d.rows = rows; d.K = K; d.trans = tr; d.blk0 = b0; return d;
    };
    T.s[0]  = seg(W1,   0L,        128,  64, 1, 0);
    T.s[1]  = seg(W2,   24576L,    64,  128, 1, 8);
    T.s[2]  = seg(W3,   49152L,    32,   64, 1, 16);
    T.s[3]  = seg(W4,   55296L,    32,   32, 1, 18);
    T.s[4]  = seg(P0,   58368L,    4096, 32, 0, 19);
    T.s[5]  = seg(P1,   451584L,   4096, 64, 0, 147);
    T.s[6]  = seg(P2,   1238016L,  4096, 128, 0, 403);
    T.s[7]  = seg(P3,   2810880L,  4096, 256, 0, 915);
    T.s[8]  = seg(P4,   5956608L,  2048, 512, 0, 1939);
    T.s[9]  = seg(P5,   9102336L,  1024, 512, 0, 2963);
    T.s[10] = seg(Ptop, 10675200L, 1000, 512, 0, 3475);
    presplit<<<dim3(3975), dim3(256), 0, stream>>>(T, planes);

    dim3 blk(256, 1, 1);
    const unsigned short* Wp1 = planes;            // plane stride 8192
    const unsigned short* Wp2 = planes + 24576;    // 8192
    const unsigned short* Wp3 = planes + 49152;    // 2048
    const unsigned short* Wp4 = planes + 55296;    // 1024
    const unsigned short* Qp0 = planes + 58368;    // 131072
    const unsigned short* Qp1 = planes + 451584;   // 262144
    const unsigned short* Qp2 = planes + 1238016;  // 524288
    const unsigned short* Qp3 = planes + 2810880;  // 1048576
    const unsigned short* Qp4 = planes + 5956608;  // 1048576
    const unsigned short* Qp5 = planes + 9102336;  // 524288
    const unsigned short* Qpt = planes + 10675200; // 512000

    // ---- MLP + leaf, 2 chunks of 131072 tokens
    for (int c = 0; c < 2; ++c) {
        const float* Xc = X + (long)c * 131072 * 64;
        // mlp1: 64->128 relu
        ht_mm<128><<<dim3(1024, 1, 1), blk, 0, stream>>>(
            Xc, Wp1, b1, h1c, 64, 128, 0L, 0L, 64, 8192L, 0L, 128, 1);
        // mlp2: 128->64 relu
        ht_mm<64><<<dim3(1024, 1, 1), blk, 0, stream>>>(
            h1c, Wp2, b2, h2c, 128, 64, 0L, 0L, 128, 8192L, 0L, 64, 1);
        // mlp3: 64->32 relu (G=32 < BG=64, masked)
        ht_mm<64><<<dim3(1024, 1, 1), blk, 0, stream>>>(
            h2c, Wp3, b3, h3c, 64, 32, 0L, 0L, 64, 2048L, 0L, 32, 1);
        // mlp4: 32->32
        ht_mm<64><<<dim3(1024, 1, 1), blk, 0, stream>>>(
            h3c, Wp4, b4, Fc, 32, 32, 0L, 0L, 32, 1024L, 0L, 32, 0);
        // leaf: t0[j][b][a] = sum_m P0[j][a][m] * F[(b,j)][m]
        ht_mm<64><<<dim3(16, 1, 64), blk, 0, stream>>>(
            Fc, Qp0, nullptr, t0 + (long)c * 2048 * 64, 32, 64,
            32L, 0L, 2048, 131072L, 262144L, 64, 0);
    }

    // ---- tree: t_l[n][b][g] = sum_a P_l[n][g][a] * t[2n][b][a]*t[2n+1][b][a]
    ht_mm<128><<<dim3(32, 1, 32), blk, 0, stream>>>(      // L1 K=64 G=128
        t0, Qp1, nullptr, t1, 64, 128, 524288L, 262144L, 64, 262144L, 524288L, 128, 0);
    ht_mm<128><<<dim3(32, 2, 16), blk, 0, stream>>>(      // L2 K=128 G=256
        t1, Qp2, nullptr, t2, 128, 256, 1048576L, 524288L, 128, 524288L, 1048576L, 256, 0);
    ht_mm<128><<<dim3(32, 4, 8), blk, 0, stream>>>(       // L3 K=256 G=512
        t2, Qp3, nullptr, t3, 256, 512, 2097152L, 1048576L, 256, 1048576L, 2097152L, 512, 0);
    ht_mm<128><<<dim3(32, 4, 4), blk, 0, stream>>>(       // L4 K=512 G=512
        t3, Qp4, nullptr, t4, 512, 512, 4194304L, 2097152L, 512, 1048576L, 2097152L, 512, 0);
    ht_mm<128><<<dim3(32, 4, 2), blk, 0, stream>>>(       // L5 K=512 G=512
        t4, Qp5, nullptr, t5, 512, 512, 4194304L, 2097152L, 512, 524288L, 2097152L, 512, 0);
    ht_mm<128><<<dim3(32, 8, 1), blk, 0, stream>>>(       // top K=512 G=1000
        t5, Qpt, nullptr, out, 512, 1000, 0L, 2097152L, 512, 512000L, 0L, 1000, 0);
}